// Round 4
// baseline (321.446 us; speedup 1.0000x reference)
//
#include <hip/hip_runtime.h>

#define NODES 50000
#define RELS  3
#define NEDGE 600000
#define FIN   128
#define FHID  64
#define FOUT  64
#define SEGS  (RELS * NODES)            // 150000 (rel, dst) segments
#define NBLK  ((SEGS + 255) / 256)      // 586 scan blocks

#define BS     250                      // nodes per dst-bucket
#define NBUK   200                      // buckets per relation (250*200 = 50000)
#define NBUKT  (RELS * NBUK)            // 600 total buckets
#define CAPLOG 12
#define CAP    (1 << CAPLOG)            // 4096 record slots/bucket (mean 3000, +20 sigma)
#define BCH    192                      // bucketize chunks per relation
#define BCHUNK (NEDGE / BCH)            // 3125 (exact)

typedef _Float16 half8 __attribute__((ext_vector_type(8)));
typedef float   floatx4 __attribute__((ext_vector_type(4)));

// ---------------- init: zero deg/bucket cursors + weight fp16 transpose ----------
__global__ __launch_bounds__(256) void init_kernel(int* __restrict__ odeg,
                                                   int* __restrict__ bcur,
                                                   const float* __restrict__ W1,
                                                   const float* __restrict__ W2,
                                                   _Float16* __restrict__ W1t,
                                                   _Float16* __restrict__ W2t) {
    int gid = blockIdx.x * 256 + threadIdx.x;
    if (gid < SEGS) {
        odeg[gid] = 0;
        if (gid < NBUKT) bcur[gid] = 0;
        return;
    }
    int g2 = gid - SEGS;
    if (g2 < RELS * FIN * FHID) {                  // W1 -> fp16 [r][j][k]
        int r = g2 / (FIN * FHID);
        int rem = g2 - r * FIN * FHID;
        int k = rem / FHID, j = rem - k * FHID;
        W1t[((size_t)r * FHID + j) * FIN + k] = (_Float16)W1[g2];
        return;
    }
    int g3 = g2 - RELS * FIN * FHID;
    if (g3 < RELS * FHID * FOUT) {                 // W2 -> fp16 [r][j][k]
        int r = g3 / (FHID * FOUT);
        int rem = g3 - r * FHID * FOUT;
        int k = rem / FOUT, j = rem - k * FOUT;
        W2t[((size_t)r * FOUT + j) * FHID + k] = (_Float16)W2[g3];
    }
}

// ---------------- phase 1: dst-bucket partition of the edge list ----------------
// Records (src<<16 | bucket<<8 | dlocal) land bucket-major with fixed CAP slots.
// LDS staging + per-block bucket histogram -> one global atomicAdd per
// (block,bucket) window reservation -> contiguous ~64-128B record runs.
// Out-degree counted here too: fire-and-forget global atomics (no return, no
// dependency); replaces the full-range LDS histogram + 28.8MB slab round-trip.
__global__ __launch_bounds__(512) void bucketize_kernel(const int* __restrict__ src,
                                                        const int* __restrict__ dst,
                                                        int* __restrict__ bcur,
                                                        int* __restrict__ odeg,
                                                        unsigned int* __restrict__ rec) {
    __shared__ unsigned int stage[BCHUNK];         // 12.5 KB
    __shared__ int bh[NBUK], bbase[NBUK], blc[NBUK];
    int chunk = blockIdx.x, r = blockIdx.y;
    for (int i = threadIdx.x; i < NBUK; i += 512) { bh[i] = 0; blc[i] = 0; }
    __syncthreads();
    size_t ebase = (size_t)r * NEDGE + (size_t)chunk * BCHUNK;
    int* od = odeg + r * NODES;
    for (int i = threadIdx.x; i < BCHUNK; i += 512) {
        int d = dst[ebase + i], s = src[ebase + i];
        int b = d / BS;                            // magic-mul
        int dl = d - b * BS;
        stage[i] = ((unsigned)s << 16) | ((unsigned)b << 8) | (unsigned)dl;
        atomicAdd(&bh[b], 1);
        atomicAdd(&od[s], 1);                      // out-degree, device scope
    }
    __syncthreads();
    for (int i = threadIdx.x; i < NBUK; i += 512)
        bbase[i] = atomicAdd(&bcur[r * NBUK + i], bh[i]);    // device-scope
    __syncthreads();
    for (int i = threadIdx.x; i < BCHUNK; i += 512) {
        unsigned u = stage[i];
        int b = (u >> 8) & 255;
        int slot = bbase[b] + atomicAdd(&blc[b], 1);
        rec[(((size_t)r * NBUK + b) << CAPLOG) + slot] = u;
    }
}

// ---------------- degrees/norms from bucket records ----------------
// One block per (bucket, rel): in-degree = LDS histogram of dlocal over the
// bucket's records (coalesced ~12KB read); outnorm finalized from odeg for the
// same 250-node window. Replaces hist(dst)+degnorm slab reduce entirely.
__global__ __launch_bounds__(256) void degbkt_kernel(const unsigned int* __restrict__ rec,
                                                     const int* __restrict__ bcur,
                                                     const int* __restrict__ odeg,
                                                     int* __restrict__ idI,
                                                     float* __restrict__ innorm,
                                                     float* __restrict__ outnorm) {
    __shared__ int cnt[BS];
    int b = blockIdx.x, r = blockIdx.y;
    for (int i = threadIdx.x; i < BS; i += 256) cnt[i] = 0;
    __syncthreads();
    int n = bcur[r * NBUK + b];
    const unsigned int* rb = rec + (((size_t)r * NBUK + b) << CAPLOG);
    for (int i = threadIdx.x; i < n; i += 256) atomicAdd(&cnt[rb[i] & 255], 1);
    __syncthreads();
    int segbase = r * NODES + b * BS;
    for (int i = threadIdx.x; i < BS; i += 256) {
        int c = cnt[i];
        idI[segbase + i] = c;
        innorm[segbase + i] = rsqrtf(fmaxf((float)c, 1.0f));
        outnorm[segbase + i] = rsqrtf(fmaxf((float)odeg[segbase + i], 1.0f));
    }
}

// ---------------- scan step 1: per-block sums ----------------
__global__ __launch_bounds__(256) void scan_sums_kernel(const int* __restrict__ idI,
                                                        int* __restrict__ partials) {
    __shared__ int s[256];
    int i = blockIdx.x * 256 + threadIdx.x;
    s[threadIdx.x] = (i < SEGS) ? idI[i] : 0;
    __syncthreads();
    for (int off = 128; off > 0; off >>= 1) {
        if (threadIdx.x < off) s[threadIdx.x] += s[threadIdx.x + off];
        __syncthreads();
    }
    if (threadIdx.x == 0) partials[blockIdx.x] = s[0];
}

// ---------------- scan step 2: re-scan partials in LDS, then block scan ----------------
__global__ __launch_bounds__(256) void scan_write_kernel(const int* __restrict__ idI,
                                                         const int* __restrict__ partials,
                                                         int* __restrict__ offs) {
    __shared__ int sp[1024];
    __shared__ int s[256];
    int tid = threadIdx.x;
    for (int i = tid; i < 1024; i += 256) sp[i] = (i < NBLK) ? partials[i] : 0;
    __syncthreads();
    for (int off = 1; off < 1024; off <<= 1) {
        int v[4];
#pragma unroll
        for (int k = 0; k < 4; ++k) { int i = tid + k * 256; v[k] = (i >= off) ? sp[i - off] : 0; }
        __syncthreads();
#pragma unroll
        for (int k = 0; k < 4; ++k) sp[tid + k * 256] += v[k];
        __syncthreads();
    }
    int bpre = (blockIdx.x == 0) ? 0 : sp[blockIdx.x - 1];   // exclusive prefix of this block
    int i = blockIdx.x * 256 + tid;
    int v = (i < SEGS) ? idI[i] : 0;
    s[tid] = v;
    __syncthreads();
    for (int off = 1; off < 256; off <<= 1) {
        int t = s[tid];
        int add = (tid >= off) ? s[tid - off] : 0;
        __syncthreads();
        s[tid] = t + add;
        __syncthreads();
    }
    if (i < SEGS) offs[i] = bpre + (s[tid] - v);
}

// ---------------- phase 2: per-bucket CSR fill ----------------
// One block per (bucket, rel): reads its records coalesced, assigns final slots
// via LDS cursors, writes edge_src inside a private ~6KB window (L2-resident,
// every line written once -> write amp ~1). Order within a segment is arbitrary.
__global__ __launch_bounds__(512) void fillbkt_kernel(const unsigned int* __restrict__ rec,
                                                      const int* __restrict__ bcur,
                                                      const int* __restrict__ offs,
                                                      unsigned short* __restrict__ edge_src) {
    __shared__ int obase[BS];
    __shared__ int lcur[BS];
    int b = blockIdx.x, r = blockIdx.y;
    int segbase = r * NODES + b * BS;
    for (int i = threadIdx.x; i < BS; i += 512) {
        obase[i] = offs[segbase + i];
        lcur[i] = 0;
    }
    __syncthreads();
    int n = bcur[r * NBUK + b];
    const unsigned int* rb = rec + (((size_t)r * NBUK + b) << CAPLOG);
    for (int i = threadIdx.x; i < n; i += 512) {
        unsigned u = rb[i];
        int dl = u & 255;
        int pos = obase[dl] + atomicAdd(&lcur[dl], 1);
        edge_src[pos] = (unsigned short)(u >> 16);
    }
}

// ---------------- layer 1 GEMM via MFMA fp16 ----------------
// Wave = 16 nodes x 192 cols (12 C-frags). A = x rows (fp32->fp16 in-reg),
// B = W1t[j][k] fp16. h output fp16 with outnorm folded.
__global__ __launch_bounds__(256, 4) void gemm1_kernel(const float* __restrict__ x,
                                                       const _Float16* __restrict__ W1t,
                                                       const float* __restrict__ outnorm,
                                                       _Float16* __restrict__ h) {
    int lane = threadIdx.x & 63;
    int wv   = threadIdx.x >> 6;
    int m = lane & 15, quad = lane >> 4;
    int n0 = (blockIdx.x * 4 + wv) * 16;
    if (n0 + 16 > NODES) n0 = NODES - 16;          // tail waves duplicate rows (same values)
    const float* xrow = x + (size_t)(n0 + m) * FIN + quad * 8;

    floatx4 acc[12];
#pragma unroll
    for (int t = 0; t < 12; ++t) acc[t] = (floatx4){0.f, 0.f, 0.f, 0.f};

#pragma unroll 1
    for (int ks = 0; ks < 4; ++ks) {               // K step of 32
        float4 xa = *(const float4*)(xrow + ks * 32);
        float4 xb = *(const float4*)(xrow + ks * 32 + 4);
        half8 a;
        a[0] = (_Float16)xa.x; a[1] = (_Float16)xa.y;
        a[2] = (_Float16)xa.z; a[3] = (_Float16)xa.w;
        a[4] = (_Float16)xb.x; a[5] = (_Float16)xb.y;
        a[6] = (_Float16)xb.z; a[7] = (_Float16)xb.w;
#pragma unroll
        for (int jt = 0; jt < 12; ++jt) {          // W1t flat: [192][128]
            const _Float16* bp = W1t + ((size_t)jt * 16 + m) * FIN + ks * 32 + quad * 8;
            half8 b = *(const half8*)bp;
            acc[jt] = __builtin_amdgcn_mfma_f32_16x16x32_f16(a, b, acc[jt], 0, 0, 0);
        }
    }

#pragma unroll
    for (int jt = 0; jt < 12; ++jt) {
        int r = jt >> 2;
        int j = (jt & 3) * 16 + m;                 // D col = lane&15
        _Float16* hb = h + (size_t)r * NODES * FHID;
        const float* on = outnorm + r * NODES;
#pragma unroll
        for (int reg = 0; reg < 4; ++reg) {
            int node = n0 + quad * 4 + reg;        // D row = quad*4+reg
            hb[(size_t)node * FHID + j] = (_Float16)(acc[jt][reg] * on[node]);
        }
    }
}

// ---------------- per-segment feature sum: lane-group local, 4-deep unrolled ----
// 8 lanes (q=0..7) share one segment; each lane sums its half8 feature slot.
__device__ __forceinline__ void seg_sum8(const _Float16* __restrict__ hb,
                                         const unsigned short* __restrict__ es,
                                         int o, int c, int q, float* __restrict__ s) {
#pragma unroll
    for (int i = 0; i < 8; ++i) s[i] = 0.f;
    int t = 0;
    for (; t + 4 <= c; t += 4) {
        int i0 = es[o + t], i1 = es[o + t + 1], i2 = es[o + t + 2], i3 = es[o + t + 3];
        half8 v0 = *(const half8*)(hb + (size_t)i0 * FHID + q * 8);
        half8 v1 = *(const half8*)(hb + (size_t)i1 * FHID + q * 8);
        half8 v2 = *(const half8*)(hb + (size_t)i2 * FHID + q * 8);
        half8 v3 = *(const half8*)(hb + (size_t)i3 * FHID + q * 8);
#pragma unroll
        for (int i = 0; i < 8; ++i) {
            s[i] += (float)v0[i];
            s[i] += (float)v1[i];
            s[i] += (float)v2[i];
            s[i] += (float)v3[i];
        }
    }
    if (t + 2 <= c) {
        int i0 = es[o + t], i1 = es[o + t + 1];
        half8 v0 = *(const half8*)(hb + (size_t)i0 * FHID + q * 8);
        half8 v1 = *(const half8*)(hb + (size_t)i1 * FHID + q * 8);
#pragma unroll
        for (int i = 0; i < 8; ++i) {
            s[i] += (float)v0[i];
            s[i] += (float)v1[i];
        }
        t += 2;
    }
    if (t < c) {
        int i0 = es[o + t];
        half8 v0 = *(const half8*)(hb + (size_t)i0 * FHID + q * 8);
#pragma unroll
        for (int i = 0; i < 8; ++i) s[i] += (float)v0[i];
    }
}

// ---------------- layer 1 gather: 8 dst per wave, no cross-lane reduce ----------
__global__ __launch_bounds__(256) void gather1_kernel(const _Float16* __restrict__ h,
                                                      const unsigned short* __restrict__ es,
                                                      const int* __restrict__ offs,
                                                      const int* __restrict__ cnt,
                                                      const float* __restrict__ innorm,
                                                      const float* __restrict__ b1,
                                                      _Float16* __restrict__ B) {
    int lane = threadIdx.x & 63;
    int wv   = threadIdx.x >> 6;
    int w    = blockIdx.x * 4 + wv;
    if (w * 8 >= NODES) return;                    // tail waves of last block
    int q    = lane & 7;
    int e8   = lane >> 3;
    int d    = w * 8 + e8;
    int c0 = cnt[d], c1 = cnt[NODES + d], c2 = cnt[2 * NODES + d];
    int o0 = offs[d], o1 = offs[NODES + d], o2 = offs[2 * NODES + d];
    float w0 = innorm[d], w1 = innorm[NODES + d], w2 = innorm[2 * NODES + d];

    float tot[8], s[8];
    seg_sum8(h, es, o0, c0, q, s);
#pragma unroll
    for (int i = 0; i < 8; ++i) tot[i] = w0 * s[i];
    seg_sum8(h + (size_t)NODES * FHID, es, o1, c1, q, s);
#pragma unroll
    for (int i = 0; i < 8; ++i) tot[i] = fmaf(w1, s[i], tot[i]);
    seg_sum8(h + 2 * (size_t)NODES * FHID, es, o2, c2, q, s);
#pragma unroll
    for (int i = 0; i < 8; ++i) tot[i] = fmaf(w2, s[i], tot[i]);

    half8 o8;
#pragma unroll
    for (int i = 0; i < 8; ++i) {
        int j = q * 8 + i;
        float bs = b1[j] + b1[FHID + j] + b1[2 * FHID + j];
        o8[i] = (_Float16)fmaxf(tot[i] + bs, 0.f);
    }
    *(half8*)(B + (size_t)d * FHID + q * 8) = o8;
}

// ---------------- layer 2 gather: 8 (r,dst) segments per wave ------------------
__global__ __launch_bounds__(256) void gather2_kernel(const _Float16* __restrict__ h1,
                                                      const unsigned short* __restrict__ es,
                                                      const int* __restrict__ offs,
                                                      const int* __restrict__ cnt,
                                                      const float* __restrict__ outnorm,
                                                      const float* __restrict__ innorm,
                                                      _Float16* __restrict__ A2) {
    int lane = threadIdx.x & 63;
    int wv   = threadIdx.x >> 6;
    int w    = blockIdx.x * 4 + wv;
    int s0   = w * 8;
    if (s0 >= SEGS) return;                        // tail waves of last block
    int q    = lane & 7;
    int e8   = lane >> 3;
    int seg  = s0 + e8;                            // NODES%8==0 -> wave never straddles r
    int o = offs[seg], c = cnt[seg];
    const float* on = outnorm + (s0 / NODES) * NODES;

    float tot[8];
#pragma unroll
    for (int i = 0; i < 8; ++i) tot[i] = 0.f;
    int t = 0;
    for (; t + 4 <= c; t += 4) {
        int i0 = es[o + t], i1 = es[o + t + 1], i2 = es[o + t + 2], i3 = es[o + t + 3];
        float w0 = on[i0], w1 = on[i1], w2 = on[i2], w3 = on[i3];
        half8 v0 = *(const half8*)(h1 + (size_t)i0 * FHID + q * 8);
        half8 v1 = *(const half8*)(h1 + (size_t)i1 * FHID + q * 8);
        half8 v2 = *(const half8*)(h1 + (size_t)i2 * FHID + q * 8);
        half8 v3 = *(const half8*)(h1 + (size_t)i3 * FHID + q * 8);
#pragma unroll
        for (int i = 0; i < 8; ++i) {
            tot[i] = fmaf(w0, (float)v0[i], tot[i]);
            tot[i] = fmaf(w1, (float)v1[i], tot[i]);
            tot[i] = fmaf(w2, (float)v2[i], tot[i]);
            tot[i] = fmaf(w3, (float)v3[i], tot[i]);
        }
    }
    if (t + 2 <= c) {
        int i0 = es[o + t], i1 = es[o + t + 1];
        float w0 = on[i0], w1 = on[i1];
        half8 v0 = *(const half8*)(h1 + (size_t)i0 * FHID + q * 8);
        half8 v1 = *(const half8*)(h1 + (size_t)i1 * FHID + q * 8);
#pragma unroll
        for (int i = 0; i < 8; ++i) {
            tot[i] = fmaf(w0, (float)v0[i], tot[i]);
            tot[i] = fmaf(w1, (float)v1[i], tot[i]);
        }
        t += 2;
    }
    if (t < c) {
        int i0 = es[o + t];
        float w0 = on[i0];
        half8 v0 = *(const half8*)(h1 + (size_t)i0 * FHID + q * 8);
#pragma unroll
        for (int i = 0; i < 8; ++i) tot[i] = fmaf(w0, (float)v0[i], tot[i]);
    }

    float inr = innorm[seg];
    half8 o8;
#pragma unroll
    for (int i = 0; i < 8; ++i) o8[i] = (_Float16)(inr * tot[i]);
    *(half8*)(A2 + (size_t)seg * FHID + q * 8) = o8;
}

// ---------------- layer 2 GEMM via MFMA fp16: out = sum_r A2[r] @ W2[r] + bias
__global__ __launch_bounds__(256, 4) void out_kernel(const _Float16* __restrict__ A2,
                                                     const _Float16* __restrict__ W2t,
                                                     const float* __restrict__ b2,
                                                     float* __restrict__ out) {
    int lane = threadIdx.x & 63;
    int wv   = threadIdx.x >> 6;
    int m = lane & 15, quad = lane >> 4;
    int n0 = (blockIdx.x * 4 + wv) * 16;
    if (n0 + 16 > NODES) n0 = NODES - 16;

    floatx4 acc[4];
#pragma unroll
    for (int t = 0; t < 4; ++t) acc[t] = (floatx4){0.f, 0.f, 0.f, 0.f};

#pragma unroll 1
    for (int kk = 0; kk < 6; ++kk) {               // (rel, 32-K-step)
        int r = kk >> 1, kb = (kk & 1) * 32;
        const _Float16* ap = A2 + ((size_t)r * NODES + n0 + m) * FHID + kb + quad * 8;
        half8 a = *(const half8*)ap;
#pragma unroll
        for (int jt = 0; jt < 4; ++jt) {
            const _Float16* bp = W2t + ((size_t)(r * FOUT + jt * 16 + m)) * FHID + kb + quad * 8;
            half8 b = *(const half8*)bp;
            acc[jt] = __builtin_amdgcn_mfma_f32_16x16x32_f16(a, b, acc[jt], 0, 0, 0);
        }
    }

#pragma unroll
    for (int jt = 0; jt < 4; ++jt) {
        int j = jt * 16 + m;
        float bs = b2[j] + b2[FOUT + j] + b2[2 * FOUT + j];
#pragma unroll
        for (int reg = 0; reg < 4; ++reg) {
            int node = n0 + quad * 4 + reg;
            out[(size_t)node * FOUT + j] = acc[jt][reg] + bs;
        }
    }
}

extern "C" void kernel_launch(void* const* d_in, const int* in_sizes, int n_in,
                              void* d_out, int out_size, void* d_ws, size_t ws_size,
                              hipStream_t stream) {
    const float* x   = (const float*)d_in[0];   // [N,128]
    const float* W1  = (const float*)d_in[1];   // [3,128,64]
    const float* b1  = (const float*)d_in[2];   // [3,64]
    const float* W2  = (const float*)d_in[3];   // [3,64,64]
    const float* b2  = (const float*)d_in[4];   // [3,64]
    const int*   src = (const int*)d_in[5];     // [3,E]
    const int*   dst = (const int*)d_in[6];     // [3,E]
    float* out = (float*)d_out;                 // [N,64]

    // ws: idI | offs | partials | bcur | odeg | edge_src(u16) | outnorm | innorm | W1t | W2t | h | B | A2
    int*   idI      = (int*)d_ws;
    int*   offs     = idI + SEGS;
    int*   partials = offs + SEGS;
    int*   bcur     = partials + 1024;                       // 600 used (1024 pad)
    int*   odeg     = bcur + 1024;                           // [3][N] out-degrees
    unsigned short* edge_src = (unsigned short*)(odeg + SEGS);               // [3E] u16
    float* outnorm  = (float*)(edge_src + (size_t)RELS * NEDGE);
    float* innorm   = outnorm + SEGS;
    _Float16* W1t   = (_Float16*)(innorm + SEGS);            // [3][64][128]
    _Float16* W2t   = W1t + (size_t)RELS * FHID * FIN;       // [3][64][64]
    _Float16* h     = W2t + (size_t)RELS * FHID * FOUT;      // [3][N][64] fp16
    _Float16* B     = h + (size_t)SEGS * FHID;               // [N][64] fp16
    _Float16* A2    = B + (size_t)NODES * FHID;              // [3][N][64] fp16
    // rec array (600*4096*4 = 9.8 MB) aliases the h region (19.2 MB): fully
    // consumed by degbkt/fillbkt before gemm1 writes h.
    unsigned int*  rec = (unsigned int*)h;

    const int GW = ((NODES / 16) + 4) / 4;        // 782 blocks of 4 waves x 16 nodes

    // CSR build + norms + weight convert:
    // init -> bucketize(+out-deg atomics) -> degbkt -> scan -> fillbkt
    init_kernel<<<(SEGS + RELS * FIN * FHID + RELS * FHID * FOUT + 255) / 256,
                  256, 0, stream>>>(odeg, bcur, W1, W2, W1t, W2t);
    bucketize_kernel<<<dim3(BCH, RELS), 512, 0, stream>>>(src, dst, bcur, odeg, rec);
    degbkt_kernel<<<dim3(NBUK, RELS), 256, 0, stream>>>(rec, bcur, odeg, idI, innorm, outnorm);
    scan_sums_kernel<<<NBLK, 256, 0, stream>>>(idI, partials);
    scan_write_kernel<<<NBLK, 256, 0, stream>>>(idI, partials, offs);
    fillbkt_kernel<<<dim3(NBUK, RELS), 512, 0, stream>>>(rec, bcur, offs, edge_src);

    // layer 1
    gemm1_kernel<<<GW, 256, 0, stream>>>(x, W1t, outnorm, h);
    gather1_kernel<<<(NODES / 8 + 3) / 4, 256, 0, stream>>>(h, edge_src, offs, idI, innorm, b1, B);

    // layer 2
    gather2_kernel<<<(SEGS / 8 + 3) / 4, 256, 0, stream>>>(B, edge_src, offs, idI, outnorm, innorm, A2);
    out_kernel<<<GW, 256, 0, stream>>>(A2, W2t, b2, out);
}

// Round 5
// 250.022 us; speedup vs baseline: 1.2857x; 1.2857x over previous
//
#include <hip/hip_runtime.h>

#define NODES 50000
#define RELS  3
#define NEDGE 600000
#define FIN   128
#define FHID  64
#define FOUT  64
#define SEGS  (RELS * NODES)            // 150000 (rel, dst) segments
#define NBLK  ((SEGS + 255) / 256)      // 586 scan blocks

#define HC     96                       // histogram chunks per src array
#define HCHUNK (NEDGE / HC)             // 6250 (exact)
#define HBYTES NODES                    // 50000 u8 bins (full node range)
#define HWORDS (HBYTES / 4)             // 12500 u32 words (50 KB LDS)

#define BS     250                      // nodes per dst-bucket
#define NBUK   200                      // buckets per relation (250*200 = 50000)
#define NBUKT  (RELS * NBUK)            // 600 total buckets
#define CAPLOG 12
#define CAP    (1 << CAPLOG)            // 4096 record slots/bucket (mean 3000, +20 sigma)
#define BCH    192                      // bucketize chunks per relation
#define BCHUNK (NEDGE / BCH)            // 3125 (exact)

typedef _Float16 half8 __attribute__((ext_vector_type(8)));
typedef float   floatx4 __attribute__((ext_vector_type(4)));

// ---------------- init: zero bucket cursors + weight fp16 transpose ----------
__global__ __launch_bounds__(256) void init_kernel(int* __restrict__ bcur,
                                                   const float* __restrict__ W1,
                                                   const float* __restrict__ W2,
                                                   _Float16* __restrict__ W1t,
                                                   _Float16* __restrict__ W2t) {
    int gid = blockIdx.x * 256 + threadIdx.x;
    if (gid < NBUKT) bcur[gid] = 0;
    int g2 = gid - 1024;
    if (g2 >= 0 && g2 < RELS * FIN * FHID) {       // W1 -> fp16 [r][j][k]
        int r = g2 / (FIN * FHID);
        int rem = g2 - r * FIN * FHID;
        int k = rem / FHID, j = rem - k * FHID;
        W1t[((size_t)r * FHID + j) * FIN + k] = (_Float16)W1[g2];
        return;
    }
    int g3 = g2 - RELS * FIN * FHID;
    if (g3 >= 0 && g3 < RELS * FHID * FOUT) {      // W2 -> fp16 [r][j][k]
        int r = g3 / (FHID * FOUT);
        int rem = g3 - r * FHID * FOUT;
        int k = rem / FOUT, j = rem - k * FOUT;
        W2t[((size_t)r * FOUT + j) * FHID + k] = (_Float16)W2[g3];
    }
}

// ---------------- out-degree: LDS-staged u8 histogram over src (3 jobs) --------
// grid = (chunk, rel). Per-(chunk,bin) count << 255 so u8 cannot overflow.
// NOTE (round-4 lesson): 1.8M random GLOBAL atomics for out-deg cost ~60us of
// coherence/RMW traffic (WRITE_SIZE 66MB) — LDS histogram + slab is 5x cheaper.
__global__ __launch_bounds__(1024) void hist_kernel(const int* __restrict__ src,
                                                    unsigned int* __restrict__ slab32) {
    __shared__ unsigned int bins[HWORDS];          // 50 KB, u8-packed counts
    int chunk = blockIdx.x, r = blockIdx.y;
    const int* arr = src + (size_t)r * NEDGE + (size_t)chunk * HCHUNK;
    for (int w = threadIdx.x; w < HWORDS; w += 1024) bins[w] = 0u;
    __syncthreads();
    for (int i = threadIdx.x; i < HCHUNK; i += 1024) {
        int v = arr[i];
        atomicAdd(&bins[v >> 2], 1u << ((v & 3) * 8));       // LDS, no return
    }
    __syncthreads();
    unsigned int* out = slab32 + ((size_t)(r * HC + chunk)) * HWORDS;
    for (int w = threadIdx.x; w < HWORDS; w += 1024) out[w] = bins[w];
}

// ---------------- phase 1: dst-bucket partition of the edge list ----------------
// Records (src<<16 | bucket<<8 | dlocal) land bucket-major with fixed CAP slots.
// LDS staging + per-block bucket histogram -> one global atomicAdd per
// (block,bucket) window reservation -> contiguous ~64-128B record runs.
__global__ __launch_bounds__(512) void bucketize_kernel(const int* __restrict__ src,
                                                        const int* __restrict__ dst,
                                                        int* __restrict__ bcur,
                                                        unsigned int* __restrict__ rec) {
    __shared__ unsigned int stage[BCHUNK];         // 12.5 KB
    __shared__ int bh[NBUK], bbase[NBUK], blc[NBUK];
    int chunk = blockIdx.x, r = blockIdx.y;
    for (int i = threadIdx.x; i < NBUK; i += 512) { bh[i] = 0; blc[i] = 0; }
    __syncthreads();
    size_t ebase = (size_t)r * NEDGE + (size_t)chunk * BCHUNK;
    for (int i = threadIdx.x; i < BCHUNK; i += 512) {
        int d = dst[ebase + i], s = src[ebase + i];
        int b = d / BS;                            // magic-mul
        int dl = d - b * BS;
        stage[i] = ((unsigned)s << 16) | ((unsigned)b << 8) | (unsigned)dl;
        atomicAdd(&bh[b], 1);
    }
    __syncthreads();
    for (int i = threadIdx.x; i < NBUK; i += 512)
        bbase[i] = atomicAdd(&bcur[r * NBUK + i], bh[i]);    // device-scope
    __syncthreads();
    for (int i = threadIdx.x; i < BCHUNK; i += 512) {
        unsigned u = stage[i];
        int b = (u >> 8) & 255;
        int slot = bbase[b] + atomicAdd(&blc[b], 1);
        rec[(((size_t)r * NBUK + b) << CAPLOG) + slot] = u;
    }
}

// ---------------- degrees/norms: in-deg from rec, out-deg from slab ------------
// One block per (bucket, rel): in-degree = LDS histogram of dlocal over the
// bucket's records (coalesced ~12KB read); out-degree = slab reduce over 96
// chunks x 250-node window (each iteration a coalesced 250B run).
__global__ __launch_bounds__(256) void degbkt_kernel(const unsigned int* __restrict__ rec,
                                                     const int* __restrict__ bcur,
                                                     const unsigned char* __restrict__ slab8,
                                                     int* __restrict__ idI,
                                                     float* __restrict__ innorm,
                                                     float* __restrict__ outnorm) {
    __shared__ int cnt[BS];
    int b = blockIdx.x, r = blockIdx.y;
    for (int i = threadIdx.x; i < BS; i += 256) cnt[i] = 0;
    __syncthreads();
    int n = bcur[r * NBUK + b];
    const unsigned int* rb = rec + (((size_t)r * NBUK + b) << CAPLOG);
    for (int i = threadIdx.x; i < n; i += 256) atomicAdd(&cnt[rb[i] & 255], 1);
    __syncthreads();
    int segbase = r * NODES + b * BS;
    const unsigned char* sl = slab8 + (size_t)r * HC * HBYTES + b * BS;
    for (int i = threadIdx.x; i < BS; i += 256) {
        int c = cnt[i];
        idI[segbase + i] = c;
        innorm[segbase + i] = rsqrtf(fmaxf((float)c, 1.0f));
        int od = 0;
#pragma unroll 4
        for (int ch = 0; ch < HC; ++ch) od += sl[(size_t)ch * HBYTES + i];
        outnorm[segbase + i] = rsqrtf(fmaxf((float)od, 1.0f));
    }
}

// ---------------- scan step 1: per-block sums ----------------
__global__ __launch_bounds__(256) void scan_sums_kernel(const int* __restrict__ idI,
                                                        int* __restrict__ partials) {
    __shared__ int s[256];
    int i = blockIdx.x * 256 + threadIdx.x;
    s[threadIdx.x] = (i < SEGS) ? idI[i] : 0;
    __syncthreads();
    for (int off = 128; off > 0; off >>= 1) {
        if (threadIdx.x < off) s[threadIdx.x] += s[threadIdx.x + off];
        __syncthreads();
    }
    if (threadIdx.x == 0) partials[blockIdx.x] = s[0];
}

// ---------------- scan step 2: re-scan partials in LDS, then block scan ----------------
__global__ __launch_bounds__(256) void scan_write_kernel(const int* __restrict__ idI,
                                                         const int* __restrict__ partials,
                                                         int* __restrict__ offs) {
    __shared__ int sp[1024];
    __shared__ int s[256];
    int tid = threadIdx.x;
    for (int i = tid; i < 1024; i += 256) sp[i] = (i < NBLK) ? partials[i] : 0;
    __syncthreads();
    for (int off = 1; off < 1024; off <<= 1) {
        int v[4];
#pragma unroll
        for (int k = 0; k < 4; ++k) { int i = tid + k * 256; v[k] = (i >= off) ? sp[i - off] : 0; }
        __syncthreads();
#pragma unroll
        for (int k = 0; k < 4; ++k) sp[tid + k * 256] += v[k];
        __syncthreads();
    }
    int bpre = (blockIdx.x == 0) ? 0 : sp[blockIdx.x - 1];   // exclusive prefix of this block
    int i = blockIdx.x * 256 + tid;
    int v = (i < SEGS) ? idI[i] : 0;
    s[tid] = v;
    __syncthreads();
    for (int off = 1; off < 256; off <<= 1) {
        int t = s[tid];
        int add = (tid >= off) ? s[tid - off] : 0;
        __syncthreads();
        s[tid] = t + add;
        __syncthreads();
    }
    if (i < SEGS) offs[i] = bpre + (s[tid] - v);
}

// ---------------- phase 2: per-bucket CSR fill ----------------
// One block per (bucket, rel): reads its records coalesced, assigns final slots
// via LDS cursors, writes edge_src inside a private ~6KB window (L2-resident,
// every line written once -> write amp ~1). Order within a segment is arbitrary.
__global__ __launch_bounds__(512) void fillbkt_kernel(const unsigned int* __restrict__ rec,
                                                      const int* __restrict__ bcur,
                                                      const int* __restrict__ offs,
                                                      unsigned short* __restrict__ edge_src) {
    __shared__ int obase[BS];
    __shared__ int lcur[BS];
    int b = blockIdx.x, r = blockIdx.y;
    int segbase = r * NODES + b * BS;
    for (int i = threadIdx.x; i < BS; i += 512) {
        obase[i] = offs[segbase + i];
        lcur[i] = 0;
    }
    __syncthreads();
    int n = bcur[r * NBUK + b];
    const unsigned int* rb = rec + (((size_t)r * NBUK + b) << CAPLOG);
    for (int i = threadIdx.x; i < n; i += 512) {
        unsigned u = rb[i];
        int dl = u & 255;
        int pos = obase[dl] + atomicAdd(&lcur[dl], 1);
        edge_src[pos] = (unsigned short)(u >> 16);
    }
}

// ---------------- layer 1 GEMM via MFMA fp16 ----------------
// Wave = 16 nodes x 192 cols (12 C-frags). A = x rows (fp32->fp16 in-reg),
// B = W1t[j][k] fp16. h output fp16 with outnorm folded.
__global__ __launch_bounds__(256, 4) void gemm1_kernel(const float* __restrict__ x,
                                                       const _Float16* __restrict__ W1t,
                                                       const float* __restrict__ outnorm,
                                                       _Float16* __restrict__ h) {
    int lane = threadIdx.x & 63;
    int wv   = threadIdx.x >> 6;
    int m = lane & 15, quad = lane >> 4;
    int n0 = (blockIdx.x * 4 + wv) * 16;
    if (n0 + 16 > NODES) n0 = NODES - 16;          // tail waves duplicate rows (same values)
    const float* xrow = x + (size_t)(n0 + m) * FIN + quad * 8;

    floatx4 acc[12];
#pragma unroll
    for (int t = 0; t < 12; ++t) acc[t] = (floatx4){0.f, 0.f, 0.f, 0.f};

#pragma unroll 1
    for (int ks = 0; ks < 4; ++ks) {               // K step of 32
        float4 xa = *(const float4*)(xrow + ks * 32);
        float4 xb = *(const float4*)(xrow + ks * 32 + 4);
        half8 a;
        a[0] = (_Float16)xa.x; a[1] = (_Float16)xa.y;
        a[2] = (_Float16)xa.z; a[3] = (_Float16)xa.w;
        a[4] = (_Float16)xb.x; a[5] = (_Float16)xb.y;
        a[6] = (_Float16)xb.z; a[7] = (_Float16)xb.w;
#pragma unroll
        for (int jt = 0; jt < 12; ++jt) {          // W1t flat: [192][128]
            const _Float16* bp = W1t + ((size_t)jt * 16 + m) * FIN + ks * 32 + quad * 8;
            half8 b = *(const half8*)bp;
            acc[jt] = __builtin_amdgcn_mfma_f32_16x16x32_f16(a, b, acc[jt], 0, 0, 0);
        }
    }

#pragma unroll
    for (int jt = 0; jt < 12; ++jt) {
        int r = jt >> 2;
        int j = (jt & 3) * 16 + m;                 // D col = lane&15
        _Float16* hb = h + (size_t)r * NODES * FHID;
        const float* on = outnorm + r * NODES;
#pragma unroll
        for (int reg = 0; reg < 4; ++reg) {
            int node = n0 + quad * 4 + reg;        // D row = quad*4+reg
            hb[(size_t)node * FHID + j] = (_Float16)(acc[jt][reg] * on[node]);
        }
    }
}

// ---------------- per-segment feature sum: lane-group local, 4-deep unrolled ----
// 8 lanes (q=0..7) share one segment; each lane sums its half8 feature slot.
__device__ __forceinline__ void seg_sum8(const _Float16* __restrict__ hb,
                                         const unsigned short* __restrict__ es,
                                         int o, int c, int q, float* __restrict__ s) {
#pragma unroll
    for (int i = 0; i < 8; ++i) s[i] = 0.f;
    int t = 0;
    for (; t + 4 <= c; t += 4) {
        int i0 = es[o + t], i1 = es[o + t + 1], i2 = es[o + t + 2], i3 = es[o + t + 3];
        half8 v0 = *(const half8*)(hb + (size_t)i0 * FHID + q * 8);
        half8 v1 = *(const half8*)(hb + (size_t)i1 * FHID + q * 8);
        half8 v2 = *(const half8*)(hb + (size_t)i2 * FHID + q * 8);
        half8 v3 = *(const half8*)(hb + (size_t)i3 * FHID + q * 8);
#pragma unroll
        for (int i = 0; i < 8; ++i) {
            s[i] += (float)v0[i];
            s[i] += (float)v1[i];
            s[i] += (float)v2[i];
            s[i] += (float)v3[i];
        }
    }
    if (t + 2 <= c) {
        int i0 = es[o + t], i1 = es[o + t + 1];
        half8 v0 = *(const half8*)(hb + (size_t)i0 * FHID + q * 8);
        half8 v1 = *(const half8*)(hb + (size_t)i1 * FHID + q * 8);
#pragma unroll
        for (int i = 0; i < 8; ++i) {
            s[i] += (float)v0[i];
            s[i] += (float)v1[i];
        }
        t += 2;
    }
    if (t < c) {
        int i0 = es[o + t];
        half8 v0 = *(const half8*)(hb + (size_t)i0 * FHID + q * 8);
#pragma unroll
        for (int i = 0; i < 8; ++i) s[i] += (float)v0[i];
    }
}

// ---------------- layer 1 gather: 8 dst per wave, no cross-lane reduce ----------
__global__ __launch_bounds__(256) void gather1_kernel(const _Float16* __restrict__ h,
                                                      const unsigned short* __restrict__ es,
                                                      const int* __restrict__ offs,
                                                      const int* __restrict__ cnt,
                                                      const float* __restrict__ innorm,
                                                      const float* __restrict__ b1,
                                                      _Float16* __restrict__ B) {
    int lane = threadIdx.x & 63;
    int wv   = threadIdx.x >> 6;
    int w    = blockIdx.x * 4 + wv;
    if (w * 8 >= NODES) return;                    // tail waves of last block
    int q    = lane & 7;
    int e8   = lane >> 3;
    int d    = w * 8 + e8;
    int c0 = cnt[d], c1 = cnt[NODES + d], c2 = cnt[2 * NODES + d];
    int o0 = offs[d], o1 = offs[NODES + d], o2 = offs[2 * NODES + d];
    float w0 = innorm[d], w1 = innorm[NODES + d], w2 = innorm[2 * NODES + d];

    float tot[8], s[8];
    seg_sum8(h, es, o0, c0, q, s);
#pragma unroll
    for (int i = 0; i < 8; ++i) tot[i] = w0 * s[i];
    seg_sum8(h + (size_t)NODES * FHID, es, o1, c1, q, s);
#pragma unroll
    for (int i = 0; i < 8; ++i) tot[i] = fmaf(w1, s[i], tot[i]);
    seg_sum8(h + 2 * (size_t)NODES * FHID, es, o2, c2, q, s);
#pragma unroll
    for (int i = 0; i < 8; ++i) tot[i] = fmaf(w2, s[i], tot[i]);

    half8 o8;
#pragma unroll
    for (int i = 0; i < 8; ++i) {
        int j = q * 8 + i;
        float bs = b1[j] + b1[FHID + j] + b1[2 * FHID + j];
        o8[i] = (_Float16)fmaxf(tot[i] + bs, 0.f);
    }
    *(half8*)(B + (size_t)d * FHID + q * 8) = o8;
}

// ---------------- layer 2 gather: 8 (r,dst) segments per wave ------------------
__global__ __launch_bounds__(256) void gather2_kernel(const _Float16* __restrict__ h1,
                                                      const unsigned short* __restrict__ es,
                                                      const int* __restrict__ offs,
                                                      const int* __restrict__ cnt,
                                                      const float* __restrict__ outnorm,
                                                      const float* __restrict__ innorm,
                                                      _Float16* __restrict__ A2) {
    int lane = threadIdx.x & 63;
    int wv   = threadIdx.x >> 6;
    int w    = blockIdx.x * 4 + wv;
    int s0   = w * 8;
    if (s0 >= SEGS) return;                        // tail waves of last block
    int q    = lane & 7;
    int e8   = lane >> 3;
    int seg  = s0 + e8;                            // NODES%8==0 -> wave never straddles r
    int o = offs[seg], c = cnt[seg];
    const float* on = outnorm + (s0 / NODES) * NODES;

    float tot[8];
#pragma unroll
    for (int i = 0; i < 8; ++i) tot[i] = 0.f;
    int t = 0;
    for (; t + 4 <= c; t += 4) {
        int i0 = es[o + t], i1 = es[o + t + 1], i2 = es[o + t + 2], i3 = es[o + t + 3];
        float w0 = on[i0], w1 = on[i1], w2 = on[i2], w3 = on[i3];
        half8 v0 = *(const half8*)(h1 + (size_t)i0 * FHID + q * 8);
        half8 v1 = *(const half8*)(h1 + (size_t)i1 * FHID + q * 8);
        half8 v2 = *(const half8*)(h1 + (size_t)i2 * FHID + q * 8);
        half8 v3 = *(const half8*)(h1 + (size_t)i3 * FHID + q * 8);
#pragma unroll
        for (int i = 0; i < 8; ++i) {
            tot[i] = fmaf(w0, (float)v0[i], tot[i]);
            tot[i] = fmaf(w1, (float)v1[i], tot[i]);
            tot[i] = fmaf(w2, (float)v2[i], tot[i]);
            tot[i] = fmaf(w3, (float)v3[i], tot[i]);
        }
    }
    if (t + 2 <= c) {
        int i0 = es[o + t], i1 = es[o + t + 1];
        float w0 = on[i0], w1 = on[i1];
        half8 v0 = *(const half8*)(h1 + (size_t)i0 * FHID + q * 8);
        half8 v1 = *(const half8*)(h1 + (size_t)i1 * FHID + q * 8);
#pragma unroll
        for (int i = 0; i < 8; ++i) {
            tot[i] = fmaf(w0, (float)v0[i], tot[i]);
            tot[i] = fmaf(w1, (float)v1[i], tot[i]);
        }
        t += 2;
    }
    if (t < c) {
        int i0 = es[o + t];
        float w0 = on[i0];
        half8 v0 = *(const half8*)(h1 + (size_t)i0 * FHID + q * 8);
#pragma unroll
        for (int i = 0; i < 8; ++i) tot[i] = fmaf(w0, (float)v0[i], tot[i]);
    }

    float inr = innorm[seg];
    half8 o8;
#pragma unroll
    for (int i = 0; i < 8; ++i) o8[i] = (_Float16)(inr * tot[i]);
    *(half8*)(A2 + (size_t)seg * FHID + q * 8) = o8;
}

// ---------------- layer 2 GEMM via MFMA fp16: out = sum_r A2[r] @ W2[r] + bias
__global__ __launch_bounds__(256, 4) void out_kernel(const _Float16* __restrict__ A2,
                                                     const _Float16* __restrict__ W2t,
                                                     const float* __restrict__ b2,
                                                     float* __restrict__ out) {
    int lane = threadIdx.x & 63;
    int wv   = threadIdx.x >> 6;
    int m = lane & 15, quad = lane >> 4;
    int n0 = (blockIdx.x * 4 + wv) * 16;
    if (n0 + 16 > NODES) n0 = NODES - 16;

    floatx4 acc[4];
#pragma unroll
    for (int t = 0; t < 4; ++t) acc[t] = (floatx4){0.f, 0.f, 0.f, 0.f};

#pragma unroll 1
    for (int kk = 0; kk < 6; ++kk) {               // (rel, 32-K-step)
        int r = kk >> 1, kb = (kk & 1) * 32;
        const _Float16* ap = A2 + ((size_t)r * NODES + n0 + m) * FHID + kb + quad * 8;
        half8 a = *(const half8*)ap;
#pragma unroll
        for (int jt = 0; jt < 4; ++jt) {
            const _Float16* bp = W2t + ((size_t)(r * FOUT + jt * 16 + m)) * FHID + kb + quad * 8;
            half8 b = *(const half8*)bp;
            acc[jt] = __builtin_amdgcn_mfma_f32_16x16x32_f16(a, b, acc[jt], 0, 0, 0);
        }
    }

#pragma unroll
    for (int jt = 0; jt < 4; ++jt) {
        int j = jt * 16 + m;
        float bs = b2[j] + b2[FOUT + j] + b2[2 * FOUT + j];
#pragma unroll
        for (int reg = 0; reg < 4; ++reg) {
            int node = n0 + quad * 4 + reg;
            out[(size_t)node * FOUT + j] = acc[jt][reg] + bs;
        }
    }
}

extern "C" void kernel_launch(void* const* d_in, const int* in_sizes, int n_in,
                              void* d_out, int out_size, void* d_ws, size_t ws_size,
                              hipStream_t stream) {
    const float* x   = (const float*)d_in[0];   // [N,128]
    const float* W1  = (const float*)d_in[1];   // [3,128,64]
    const float* b1  = (const float*)d_in[2];   // [3,64]
    const float* W2  = (const float*)d_in[3];   // [3,64,64]
    const float* b2  = (const float*)d_in[4];   // [3,64]
    const int*   src = (const int*)d_in[5];     // [3,E]
    const int*   dst = (const int*)d_in[6];     // [3,E]
    float* out = (float*)d_out;                 // [N,64]

    // ws: idI | offs | partials | bcur | edge_src(u16) | outnorm | innorm | W1t | W2t | h | B | A2
    int*   idI      = (int*)d_ws;
    int*   offs     = idI + SEGS;
    int*   partials = offs + SEGS;
    int*   bcur     = partials + 1024;                       // 600 used (1024 pad)
    unsigned short* edge_src = (unsigned short*)(bcur + 1024);               // [3E] u16
    float* outnorm  = (float*)(edge_src + (size_t)RELS * NEDGE);
    float* innorm   = outnorm + SEGS;
    _Float16* W1t   = (_Float16*)(innorm + SEGS);            // [3][64][128]
    _Float16* W2t   = W1t + (size_t)RELS * FHID * FIN;       // [3][64][64]
    _Float16* h     = W2t + (size_t)RELS * FHID * FOUT;      // [3][N][64] fp16
    _Float16* B     = h + (size_t)SEGS * FHID;               // [N][64] fp16
    _Float16* A2    = B + (size_t)NODES * FHID;              // [3][N][64] fp16
    // rec (600*4096*4 = 9.8 MB) + u8 src-slab (3*96*50000 = 14.4 MB) alias the
    // h|B region (25.6 MB): both fully consumed by degbkt/fillbkt before
    // gemm1/gather1 write those regions.
    unsigned int*  rec    = (unsigned int*)h;
    unsigned int*  slab32 = rec + (size_t)NBUKT * CAP;
    unsigned char* slab8  = (unsigned char*)slab32;

    const int GW = ((NODES / 16) + 4) / 4;        // 782 blocks of 4 waves x 16 nodes

    // CSR build + norms + weight convert:
    // init -> hist(src) -> bucketize -> degbkt -> scan -> fillbkt
    init_kernel<<<(1024 + RELS * FIN * FHID + RELS * FHID * FOUT + 255) / 256,
                  256, 0, stream>>>(bcur, W1, W2, W1t, W2t);
    hist_kernel<<<dim3(HC, RELS), 1024, 0, stream>>>(src, slab32);
    bucketize_kernel<<<dim3(BCH, RELS), 512, 0, stream>>>(src, dst, bcur, rec);
    degbkt_kernel<<<dim3(NBUK, RELS), 256, 0, stream>>>(rec, bcur, slab8, idI, innorm, outnorm);
    scan_sums_kernel<<<NBLK, 256, 0, stream>>>(idI, partials);
    scan_write_kernel<<<NBLK, 256, 0, stream>>>(idI, partials, offs);
    fillbkt_kernel<<<dim3(NBUK, RELS), 512, 0, stream>>>(rec, bcur, offs, edge_src);

    // layer 1
    gemm1_kernel<<<GW, 256, 0, stream>>>(x, W1t, outnorm, h);
    gather1_kernel<<<(NODES / 8 + 3) / 4, 256, 0, stream>>>(h, edge_src, offs, idI, innorm, b1, B);

    // layer 2
    gather2_kernel<<<(SEGS / 8 + 3) / 4, 256, 0, stream>>>(B, edge_src, offs, idI, outnorm, innorm, A2);
    out_kernel<<<GW, 256, 0, stream>>>(A2, W2t, b2, out);
}

// Round 6
// 238.504 us; speedup vs baseline: 1.3478x; 1.0483x over previous
//
#include <hip/hip_runtime.h>

#define NODES 50000
#define RELS  3
#define NEDGE 600000
#define FIN   128
#define FHID  64
#define FOUT  64
#define SEGS  (RELS * NODES)            // 150000 (rel, dst) segments

#define HC     96                       // histogram chunks per src array
#define HCHUNK (NEDGE / HC)             // 6250 (exact)
#define HBYTES NODES                    // 50000 u8 bins (full node range)
#define HWORDS (HBYTES / 4)             // 12500 u32 words (50 KB LDS)

#define BS     250                      // nodes per dst-bucket
#define NBUK   200                      // buckets per relation (250*200 = 50000)
#define NBUKT  (RELS * NBUK)            // 600 total buckets
#define CAPLOG 12
#define CAP    (1 << CAPLOG)            // 4096 record slots/bucket (mean 3000, +20 sigma)
#define BCH    192                      // bucketize chunks per relation
#define BCHUNK (NEDGE / BCH)            // 3125 (exact)

typedef _Float16 half8 __attribute__((ext_vector_type(8)));
typedef float   floatx4 __attribute__((ext_vector_type(4)));

// ---------------- out-degree histogram over src (+ folded init) ----------------
// grid = (chunk, rel). Per-(chunk,bin) count << 255 so u8 cannot overflow.
// r==0 blocks additionally zero bcur and do the weight fp16 transpose with their
// spare threads (96x1024 = 98304 >= 600 + 36864 + 12288) — saves the init launch.
// NOTE (round-4 lesson): 1.8M random GLOBAL atomics for out-deg cost ~60us of
// coherence/RMW traffic — LDS histogram + slab is 5x cheaper.
__global__ __launch_bounds__(1024) void hist_kernel(const int* __restrict__ src,
                                                    unsigned int* __restrict__ slab32,
                                                    int* __restrict__ bcur,
                                                    const float* __restrict__ W1,
                                                    const float* __restrict__ W2,
                                                    _Float16* __restrict__ W1t,
                                                    _Float16* __restrict__ W2t) {
    __shared__ unsigned int bins[HWORDS];          // 50 KB, u8-packed counts
    int chunk = blockIdx.x, r = blockIdx.y;
    const int* arr = src + (size_t)r * NEDGE + (size_t)chunk * HCHUNK;
    for (int w = threadIdx.x; w < HWORDS; w += 1024) bins[w] = 0u;
    __syncthreads();
    for (int i = threadIdx.x; i < HCHUNK; i += 1024) {
        int v = arr[i];
        atomicAdd(&bins[v >> 2], 1u << ((v & 3) * 8));       // LDS, no return
    }
    __syncthreads();
    unsigned int* out = slab32 + ((size_t)(r * HC + chunk)) * HWORDS;
    for (int w = threadIdx.x; w < HWORDS; w += 1024) out[w] = bins[w];

    if (r == 0) {                                  // folded init work
        int gid = chunk * 1024 + threadIdx.x;
        if (gid < NBUKT) bcur[gid] = 0;
        int g2 = gid - 1024;
        if (g2 >= 0 && g2 < RELS * FIN * FHID) {   // W1 -> fp16 [r][j][k]
            int rr = g2 / (FIN * FHID);
            int rem = g2 - rr * FIN * FHID;
            int k = rem / FHID, j = rem - k * FHID;
            W1t[((size_t)rr * FHID + j) * FIN + k] = (_Float16)W1[g2];
            return;
        }
        int g3 = g2 - RELS * FIN * FHID;
        if (g3 >= 0 && g3 < RELS * FHID * FOUT) {  // W2 -> fp16 [r][j][k]
            int rr = g3 / (FHID * FOUT);
            int rem = g3 - rr * FHID * FOUT;
            int k = rem / FOUT, j = rem - k * FOUT;
            W2t[((size_t)rr * FOUT + j) * FHID + k] = (_Float16)W2[g3];
        }
    }
}

// ---------------- phase 1: dst-bucket partition of the edge list ----------------
// Records (src<<16 | bucket<<8 | dlocal) land bucket-major with fixed CAP slots.
// LDS staging + per-block bucket histogram -> one global atomicAdd per
// (block,bucket) window reservation -> contiguous ~64-128B record runs.
__global__ __launch_bounds__(512) void bucketize_kernel(const int* __restrict__ src,
                                                        const int* __restrict__ dst,
                                                        int* __restrict__ bcur,
                                                        unsigned int* __restrict__ rec) {
    __shared__ unsigned int stage[BCHUNK];         // 12.5 KB
    __shared__ int bh[NBUK], bbase[NBUK], blc[NBUK];
    int chunk = blockIdx.x, r = blockIdx.y;
    for (int i = threadIdx.x; i < NBUK; i += 512) { bh[i] = 0; blc[i] = 0; }
    __syncthreads();
    size_t ebase = (size_t)r * NEDGE + (size_t)chunk * BCHUNK;
    for (int i = threadIdx.x; i < BCHUNK; i += 512) {
        int d = dst[ebase + i], s = src[ebase + i];
        int b = d / BS;                            // magic-mul
        int dl = d - b * BS;
        stage[i] = ((unsigned)s << 16) | ((unsigned)b << 8) | (unsigned)dl;
        atomicAdd(&bh[b], 1);
    }
    __syncthreads();
    for (int i = threadIdx.x; i < NBUK; i += 512)
        bbase[i] = atomicAdd(&bcur[r * NBUK + i], bh[i]);    // device-scope
    __syncthreads();
    for (int i = threadIdx.x; i < BCHUNK; i += 512) {
        unsigned u = stage[i];
        int b = (u >> 8) & 255;
        int slot = bbase[b] + atomicAdd(&blc[b], 1);
        rec[(((size_t)r * NBUK + b) << CAPLOG) + slot] = u;
    }
}

// ---------------- merged degrees/norms/offsets/CSR-fill per (bucket, rel) -------
// Replaces degbkt + scan_sums + scan_write + fillbkt (4 dispatches -> 1):
//  * in-degree cnt[250]   = LDS histogram of dlocal over the bucket's records
//  * bucket prefix bpre   = sum of bcur[< gbid]  (bcur IS the per-bucket segment
//    total, and bucket order == segment order, so the global scan decomposes)
//  * offs                 = bpre + exclusive_scan(cnt)  (250-elem LDS scan)
//  * out-degree           = slab reduce over 96 chunks x 250-node window
//  * CSR fill             = rec re-read (L2-hot), slots via LDS cursors
__global__ __launch_bounds__(512) void degfill_kernel(const unsigned int* __restrict__ rec,
                                                      const int* __restrict__ bcur,
                                                      const unsigned char* __restrict__ slab8,
                                                      int* __restrict__ idI,
                                                      float* __restrict__ innorm,
                                                      float* __restrict__ outnorm,
                                                      int* __restrict__ offs,
                                                      unsigned short* __restrict__ edge_src) {
    __shared__ int cnt[BS], lcur[BS], obase[BS];
    __shared__ int red[512];
    int tid = threadIdx.x;
    int b = blockIdx.x, r = blockIdx.y;
    int gbid = r * NBUK + b;
    for (int i = tid; i < BS; i += 512) { cnt[i] = 0; lcur[i] = 0; }
    __syncthreads();
    int n = bcur[gbid];
    const unsigned int* rb = rec + ((size_t)gbid << CAPLOG);
    for (int i = tid; i < n; i += 512) atomicAdd(&cnt[rb[i] & 255], 1);
    // bucket prefix: sum bcur[0..gbid-1] (600 ints, L2-hot)
    int p = 0;
    for (int i = tid; i < gbid; i += 512) p += bcur[i];
    red[tid] = p;
    __syncthreads();
    for (int off = 256; off > 0; off >>= 1) {
        if (tid < off) red[tid] += red[tid + off];
        __syncthreads();
    }
    int bpre = red[0];
    int v = (tid < BS) ? cnt[tid] : 0;             // cnt final (syncs above)
    __syncthreads();
    red[tid] = v;                                  // 250-elem scan (padded to 512)
    __syncthreads();
    for (int off = 1; off < 512; off <<= 1) {
        int add = (tid >= off) ? red[tid - off] : 0;
        __syncthreads();
        red[tid] += add;
        __syncthreads();
    }
    int segbase = r * NODES + b * BS;
    if (tid < BS) {
        int o = bpre + (red[tid] - v);             // exclusive prefix
        obase[tid] = o;
        offs[segbase + tid] = o;
        idI[segbase + tid] = v;
        innorm[segbase + tid] = rsqrtf(fmaxf((float)v, 1.0f));
        int od = 0;
        const unsigned char* sl = slab8 + (size_t)r * HC * HBYTES + b * BS;
#pragma unroll 4
        for (int ch = 0; ch < HC; ++ch) od += sl[(size_t)ch * HBYTES + tid];
        outnorm[segbase + tid] = rsqrtf(fmaxf((float)od, 1.0f));
    }
    __syncthreads();
    for (int i = tid; i < n; i += 512) {           // CSR fill, rec L2-hot
        unsigned u = rb[i];
        int dl = u & 255;
        int pos = obase[dl] + atomicAdd(&lcur[dl], 1);
        edge_src[pos] = (unsigned short)(u >> 16);
    }
}

// ---------------- layer 1 GEMM via MFMA fp16 ----------------
// Wave = 16 nodes x 192 cols (12 C-frags). A = x rows (fp32->fp16 in-reg),
// B = W1t[j][k] fp16. h output fp16 with outnorm folded.
__global__ __launch_bounds__(256, 4) void gemm1_kernel(const float* __restrict__ x,
                                                       const _Float16* __restrict__ W1t,
                                                       const float* __restrict__ outnorm,
                                                       _Float16* __restrict__ h) {
    int lane = threadIdx.x & 63;
    int wv   = threadIdx.x >> 6;
    int m = lane & 15, quad = lane >> 4;
    int n0 = (blockIdx.x * 4 + wv) * 16;
    if (n0 + 16 > NODES) n0 = NODES - 16;          // tail waves duplicate rows (same values)
    const float* xrow = x + (size_t)(n0 + m) * FIN + quad * 8;

    floatx4 acc[12];
#pragma unroll
    for (int t = 0; t < 12; ++t) acc[t] = (floatx4){0.f, 0.f, 0.f, 0.f};

#pragma unroll 1
    for (int ks = 0; ks < 4; ++ks) {               // K step of 32
        float4 xa = *(const float4*)(xrow + ks * 32);
        float4 xb = *(const float4*)(xrow + ks * 32 + 4);
        half8 a;
        a[0] = (_Float16)xa.x; a[1] = (_Float16)xa.y;
        a[2] = (_Float16)xa.z; a[3] = (_Float16)xa.w;
        a[4] = (_Float16)xb.x; a[5] = (_Float16)xb.y;
        a[6] = (_Float16)xb.z; a[7] = (_Float16)xb.w;
#pragma unroll
        for (int jt = 0; jt < 12; ++jt) {          // W1t flat: [192][128]
            const _Float16* bp = W1t + ((size_t)jt * 16 + m) * FIN + ks * 32 + quad * 8;
            half8 b = *(const half8*)bp;
            acc[jt] = __builtin_amdgcn_mfma_f32_16x16x32_f16(a, b, acc[jt], 0, 0, 0);
        }
    }

#pragma unroll
    for (int jt = 0; jt < 12; ++jt) {
        int r = jt >> 2;
        int j = (jt & 3) * 16 + m;                 // D col = lane&15
        _Float16* hb = h + (size_t)r * NODES * FHID;
        const float* on = outnorm + r * NODES;
#pragma unroll
        for (int reg = 0; reg < 4; ++reg) {
            int node = n0 + quad * 4 + reg;        // D row = quad*4+reg
            hb[(size_t)node * FHID + j] = (_Float16)(acc[jt][reg] * on[node]);
        }
    }
}

// ---------------- per-segment feature sum: lane-group local, 8-deep unrolled ----
// 8 lanes (q=0..7) share one segment; each lane sums its half8 feature slot.
// Unroll 8 (was 4): keeps 8 independent 128B row-fetches in flight per group —
// the gathers are latency-bound (occupancy already ~73%, HBM ~21%).
__device__ __forceinline__ void seg_sum8(const _Float16* __restrict__ hb,
                                         const unsigned short* __restrict__ es,
                                         int o, int c, int q, float* __restrict__ s) {
#pragma unroll
    for (int i = 0; i < 8; ++i) s[i] = 0.f;
    int t = 0;
    for (; t + 8 <= c; t += 8) {
        int ix[8];
        half8 v[8];
#pragma unroll
        for (int k = 0; k < 8; ++k) ix[k] = es[o + t + k];
#pragma unroll
        for (int k = 0; k < 8; ++k) v[k] = *(const half8*)(hb + (size_t)ix[k] * FHID + q * 8);
#pragma unroll
        for (int k = 0; k < 8; ++k)
#pragma unroll
            for (int i = 0; i < 8; ++i) s[i] += (float)v[k][i];
    }
    if (t + 4 <= c) {
        int ix[4];
        half8 v[4];
#pragma unroll
        for (int k = 0; k < 4; ++k) ix[k] = es[o + t + k];
#pragma unroll
        for (int k = 0; k < 4; ++k) v[k] = *(const half8*)(hb + (size_t)ix[k] * FHID + q * 8);
#pragma unroll
        for (int k = 0; k < 4; ++k)
#pragma unroll
            for (int i = 0; i < 8; ++i) s[i] += (float)v[k][i];
        t += 4;
    }
    if (t + 2 <= c) {
        int i0 = es[o + t], i1 = es[o + t + 1];
        half8 v0 = *(const half8*)(hb + (size_t)i0 * FHID + q * 8);
        half8 v1 = *(const half8*)(hb + (size_t)i1 * FHID + q * 8);
#pragma unroll
        for (int i = 0; i < 8; ++i) {
            s[i] += (float)v0[i];
            s[i] += (float)v1[i];
        }
        t += 2;
    }
    if (t < c) {
        int i0 = es[o + t];
        half8 v0 = *(const half8*)(hb + (size_t)i0 * FHID + q * 8);
#pragma unroll
        for (int i = 0; i < 8; ++i) s[i] += (float)v0[i];
    }
}

// ---------------- layer 1 gather: 8 dst per wave, no cross-lane reduce ----------
__global__ __launch_bounds__(256) void gather1_kernel(const _Float16* __restrict__ h,
                                                      const unsigned short* __restrict__ es,
                                                      const int* __restrict__ offs,
                                                      const int* __restrict__ cnt,
                                                      const float* __restrict__ innorm,
                                                      const float* __restrict__ b1,
                                                      _Float16* __restrict__ B) {
    int lane = threadIdx.x & 63;
    int wv   = threadIdx.x >> 6;
    int w    = blockIdx.x * 4 + wv;
    if (w * 8 >= NODES) return;                    // tail waves of last block
    int q    = lane & 7;
    int e8   = lane >> 3;
    int d    = w * 8 + e8;
    int c0 = cnt[d], c1 = cnt[NODES + d], c2 = cnt[2 * NODES + d];
    int o0 = offs[d], o1 = offs[NODES + d], o2 = offs[2 * NODES + d];
    float w0 = innorm[d], w1 = innorm[NODES + d], w2 = innorm[2 * NODES + d];

    float tot[8], s[8];
    seg_sum8(h, es, o0, c0, q, s);
#pragma unroll
    for (int i = 0; i < 8; ++i) tot[i] = w0 * s[i];
    seg_sum8(h + (size_t)NODES * FHID, es, o1, c1, q, s);
#pragma unroll
    for (int i = 0; i < 8; ++i) tot[i] = fmaf(w1, s[i], tot[i]);
    seg_sum8(h + 2 * (size_t)NODES * FHID, es, o2, c2, q, s);
#pragma unroll
    for (int i = 0; i < 8; ++i) tot[i] = fmaf(w2, s[i], tot[i]);

    half8 o8;
#pragma unroll
    for (int i = 0; i < 8; ++i) {
        int j = q * 8 + i;
        float bs = b1[j] + b1[FHID + j] + b1[2 * FHID + j];
        o8[i] = (_Float16)fmaxf(tot[i] + bs, 0.f);
    }
    *(half8*)(B + (size_t)d * FHID + q * 8) = o8;
}

// ---------------- layer 2 gather: 8 (r,dst) segments per wave, 8-deep unroll ----
__global__ __launch_bounds__(256) void gather2_kernel(const _Float16* __restrict__ h1,
                                                      const unsigned short* __restrict__ es,
                                                      const int* __restrict__ offs,
                                                      const int* __restrict__ cnt,
                                                      const float* __restrict__ outnorm,
                                                      const float* __restrict__ innorm,
                                                      _Float16* __restrict__ A2) {
    int lane = threadIdx.x & 63;
    int wv   = threadIdx.x >> 6;
    int w    = blockIdx.x * 4 + wv;
    int s0   = w * 8;
    if (s0 >= SEGS) return;                        // tail waves of last block
    int q    = lane & 7;
    int e8   = lane >> 3;
    int seg  = s0 + e8;                            // NODES%8==0 -> wave never straddles r
    int o = offs[seg], c = cnt[seg];
    const float* on = outnorm + (s0 / NODES) * NODES;

    float tot[8];
#pragma unroll
    for (int i = 0; i < 8; ++i) tot[i] = 0.f;
    int t = 0;
    for (; t + 8 <= c; t += 8) {
        int ix[8];
        float wk[8];
        half8 v[8];
#pragma unroll
        for (int k = 0; k < 8; ++k) ix[k] = es[o + t + k];
#pragma unroll
        for (int k = 0; k < 8; ++k) wk[k] = on[ix[k]];
#pragma unroll
        for (int k = 0; k < 8; ++k) v[k] = *(const half8*)(h1 + (size_t)ix[k] * FHID + q * 8);
#pragma unroll
        for (int k = 0; k < 8; ++k)
#pragma unroll
            for (int i = 0; i < 8; ++i) tot[i] = fmaf(wk[k], (float)v[k][i], tot[i]);
    }
    if (t + 4 <= c) {
        int ix[4];
        float wk[4];
        half8 v[4];
#pragma unroll
        for (int k = 0; k < 4; ++k) ix[k] = es[o + t + k];
#pragma unroll
        for (int k = 0; k < 4; ++k) wk[k] = on[ix[k]];
#pragma unroll
        for (int k = 0; k < 4; ++k) v[k] = *(const half8*)(h1 + (size_t)ix[k] * FHID + q * 8);
#pragma unroll
        for (int k = 0; k < 4; ++k)
#pragma unroll
            for (int i = 0; i < 8; ++i) tot[i] = fmaf(wk[k], (float)v[k][i], tot[i]);
        t += 4;
    }
    if (t + 2 <= c) {
        int i0 = es[o + t], i1 = es[o + t + 1];
        float w0 = on[i0], w1 = on[i1];
        half8 v0 = *(const half8*)(h1 + (size_t)i0 * FHID + q * 8);
        half8 v1 = *(const half8*)(h1 + (size_t)i1 * FHID + q * 8);
#pragma unroll
        for (int i = 0; i < 8; ++i) {
            tot[i] = fmaf(w0, (float)v0[i], tot[i]);
            tot[i] = fmaf(w1, (float)v1[i], tot[i]);
        }
        t += 2;
    }
    if (t < c) {
        int i0 = es[o + t];
        float w0 = on[i0];
        half8 v0 = *(const half8*)(h1 + (size_t)i0 * FHID + q * 8);
#pragma unroll
        for (int i = 0; i < 8; ++i) tot[i] = fmaf(w0, (float)v0[i], tot[i]);
    }

    float inr = innorm[seg];
    half8 o8;
#pragma unroll
    for (int i = 0; i < 8; ++i) o8[i] = (_Float16)(inr * tot[i]);
    *(half8*)(A2 + (size_t)seg * FHID + q * 8) = o8;
}

// ---------------- layer 2 GEMM via MFMA fp16: out = sum_r A2[r] @ W2[r] + bias
__global__ __launch_bounds__(256, 4) void out_kernel(const _Float16* __restrict__ A2,
                                                     const _Float16* __restrict__ W2t,
                                                     const float* __restrict__ b2,
                                                     float* __restrict__ out) {
    int lane = threadIdx.x & 63;
    int wv   = threadIdx.x >> 6;
    int m = lane & 15, quad = lane >> 4;
    int n0 = (blockIdx.x * 4 + wv) * 16;
    if (n0 + 16 > NODES) n0 = NODES - 16;

    floatx4 acc[4];
#pragma unroll
    for (int t = 0; t < 4; ++t) acc[t] = (floatx4){0.f, 0.f, 0.f, 0.f};

#pragma unroll 1
    for (int kk = 0; kk < 6; ++kk) {               // (rel, 32-K-step)
        int r = kk >> 1, kb = (kk & 1) * 32;
        const _Float16* ap = A2 + ((size_t)r * NODES + n0 + m) * FHID + kb + quad * 8;
        half8 a = *(const half8*)ap;
#pragma unroll
        for (int jt = 0; jt < 4; ++jt) {
            const _Float16* bp = W2t + ((size_t)(r * FOUT + jt * 16 + m)) * FHID + kb + quad * 8;
            half8 b = *(const half8*)bp;
            acc[jt] = __builtin_amdgcn_mfma_f32_16x16x32_f16(a, b, acc[jt], 0, 0, 0);
        }
    }

#pragma unroll
    for (int jt = 0; jt < 4; ++jt) {
        int j = jt * 16 + m;
        float bs = b2[j] + b2[FOUT + j] + b2[2 * FOUT + j];
#pragma unroll
        for (int reg = 0; reg < 4; ++reg) {
            int node = n0 + quad * 4 + reg;
            out[(size_t)node * FOUT + j] = acc[jt][reg] + bs;
        }
    }
}

extern "C" void kernel_launch(void* const* d_in, const int* in_sizes, int n_in,
                              void* d_out, int out_size, void* d_ws, size_t ws_size,
                              hipStream_t stream) {
    const float* x   = (const float*)d_in[0];   // [N,128]
    const float* W1  = (const float*)d_in[1];   // [3,128,64]
    const float* b1  = (const float*)d_in[2];   // [3,64]
    const float* W2  = (const float*)d_in[3];   // [3,64,64]
    const float* b2  = (const float*)d_in[4];   // [3,64]
    const int*   src = (const int*)d_in[5];     // [3,E]
    const int*   dst = (const int*)d_in[6];     // [3,E]
    float* out = (float*)d_out;                 // [N,64]

    // ws: idI | offs | bcur | edge_src(u16) | outnorm | innorm | W1t | W2t | h | B | A2
    int*   idI      = (int*)d_ws;
    int*   offs     = idI + SEGS;
    int*   bcur     = offs + SEGS;                           // 600 used (1024 pad)
    unsigned short* edge_src = (unsigned short*)(bcur + 1024);               // [3E] u16
    float* outnorm  = (float*)(edge_src + (size_t)RELS * NEDGE);
    float* innorm   = outnorm + SEGS;
    _Float16* W1t   = (_Float16*)(innorm + SEGS);            // [3][64][128]
    _Float16* W2t   = W1t + (size_t)RELS * FHID * FIN;       // [3][64][64]
    _Float16* h     = W2t + (size_t)RELS * FHID * FOUT;      // [3][N][64] fp16
    _Float16* B     = h + (size_t)SEGS * FHID;               // [N][64] fp16
    _Float16* A2    = B + (size_t)NODES * FHID;              // [3][N][64] fp16
    // rec (600*4096*4 = 9.8 MB) + u8 src-slab (3*96*50000 = 14.4 MB) alias the
    // h|B region (25.6 MB): both fully consumed by degfill before
    // gemm1/gather1 write those regions.
    unsigned int*  rec    = (unsigned int*)h;
    unsigned int*  slab32 = rec + (size_t)NBUKT * CAP;
    unsigned char* slab8  = (unsigned char*)slab32;

    const int GW = ((NODES / 16) + 4) / 4;        // 782 blocks of 4 waves x 16 nodes

    // CSR build + norms + weight convert (7 dispatches total, was 11):
    // hist(+init) -> bucketize -> degfill(deg+norm+scan+fill)
    hist_kernel<<<dim3(HC, RELS), 1024, 0, stream>>>(src, slab32, bcur, W1, W2, W1t, W2t);
    bucketize_kernel<<<dim3(BCH, RELS), 512, 0, stream>>>(src, dst, bcur, rec);
    degfill_kernel<<<dim3(NBUK, RELS), 512, 0, stream>>>(rec, bcur, slab8, idI, innorm,
                                                         outnorm, offs, edge_src);

    // layer 1
    gemm1_kernel<<<GW, 256, 0, stream>>>(x, W1t, outnorm, h);
    gather1_kernel<<<(NODES / 8 + 3) / 4, 256, 0, stream>>>(h, edge_src, offs, idI, innorm, b1, B);

    // layer 2
    gather2_kernel<<<(SEGS / 8 + 3) / 4, 256, 0, stream>>>(B, edge_src, offs, idI, outnorm, innorm, A2);
    out_kernel<<<GW, 256, 0, stream>>>(A2, W2t, b2, out);
}